// Round 11
// baseline (130.405 us; speedup 1.0000x reference)
//
#include <hip/hip_runtime.h>

// MLP: 64 × (Linear(5,5)+ReLU) then Linear(5,1), BATCH = 1048576 rows.
// fp32 VALU compute-bound; scalar v_fma_f32 is the fp32 peak on CDNA4.
//
// R11: FORCED register double-buffer prefetch via inline asm.
// Law from R1-R10: dur ≈ 0.852 × (VALU-slots/row/layer) / VALUBusy.
// R3 won amortization (37 slots/row, 4 rows/thread) but stalled (65%);
// R10 won busy (84%) but paid 59 slots/row. Compiler never keeps a
// prefetched weight tile live (R8/R9/R10: VGPR 16-32). Inline-asm
// global_load_dwordx4 with "=v" outputs CANNOT be discarded:
//   per layer: one asm block = s_waitcnt vmcnt(0) (current tile ready;
//   tile tied "+v" so consumers can't hoist) + 8 loads of next layer
//   into the other buffer. Fully unrolled, A/B alternation = zero movs.
// 65th zero-layer absorbs the last prefetch; tied drain protects the
// epilogue from async writeback clobber of dead asm dest regs.
// Per layer (4 rows): 100 fma (bias = first fma's VOP3 addend) + 20 max
// = 120 VALU + 8 VMEM + 1 wait ≈ 31 slots/row — both knobs at once.

#define MLP_DEPTH 64
#define MLP_D 5
#define ROWS 4

typedef float f4 __attribute__((ext_vector_type(4)));

// d_ws: layers 0..63 at [l*32]: k<25 -> W[j*5+i] (j-major); 25..29 -> b[j];
// 30,31 pad. Layer 64 = zeros (prefetch sink). Tail at [65*32]: W_out[0..4],
// b_out, pad, pad. Total 65*32+8 = 2088 floats = 8352 B.
__global__ __launch_bounds__(256) void MLP_prep_kernel(
    const float* __restrict__ Ws, const float* __restrict__ bs,
    const float* __restrict__ W_out, const float* __restrict__ b_out,
    float* __restrict__ ws)
{
    const int idx = blockIdx.x * blockDim.x + threadIdx.x;
    if (idx < 65 * 32) {
        const int l = idx >> 5, k = idx & 31;
        float v = 0.0f;
        if (l < MLP_DEPTH) {
            if (k < 25) v = Ws[l * 25 + k];
            else if (k < 30) v = bs[l * MLP_D + (k - 25)];
        }
        ws[idx] = v;
    } else if (idx < 65 * 32 + 8) {
        const int k = idx - 65 * 32;
        float v = 0.0f;
        if (k < MLP_D) v = W_out[k];
        else if (k == MLP_D) v = b_out[0];
        ws[idx] = v;
    }
}

// Wait for the in-flight loads of buffer C (tied "+v"), then prefetch the
// next layer (ptr) into buffer N. One asm block => fixed order:
// consumers of C must follow (they depend on C "written" here).
#define PREFETCH_WAIT(N0,N1,N2,N3,N4,N5,N6,N7, C0,C1,C2,C3,C4,C5,C6,C7, P) \
    asm volatile( \
        "s_waitcnt vmcnt(0)\n\t" \
        "global_load_dwordx4 %0, %16, off\n\t" \
        "global_load_dwordx4 %1, %16, off offset:16\n\t" \
        "global_load_dwordx4 %2, %16, off offset:32\n\t" \
        "global_load_dwordx4 %3, %16, off offset:48\n\t" \
        "global_load_dwordx4 %4, %16, off offset:64\n\t" \
        "global_load_dwordx4 %5, %16, off offset:80\n\t" \
        "global_load_dwordx4 %6, %16, off offset:96\n\t" \
        "global_load_dwordx4 %7, %16, off offset:112" \
        : "=v"(N0),"=v"(N1),"=v"(N2),"=v"(N3), \
          "=v"(N4),"=v"(N5),"=v"(N6),"=v"(N7), \
          "+v"(C0),"+v"(C1),"+v"(C2),"+v"(C3), \
          "+v"(C4),"+v"(C5),"+v"(C6),"+v"(C7) \
        : "v"(P))

__device__ __forceinline__ void layer_step(
    float (&h)[ROWS][MLP_D],
    f4 c0, f4 c1, f4 c2, f4 c3, f4 c4, f4 c5, f4 c6, f4 c7)
{
    const float W[32] = {
        c0.x, c0.y, c0.z, c0.w,  c1.x, c1.y, c1.z, c1.w,
        c2.x, c2.y, c2.z, c2.w,  c3.x, c3.y, c3.z, c3.w,
        c4.x, c4.y, c4.z, c4.w,  c5.x, c5.y, c5.z, c5.w,
        c6.x, c6.y, c6.z, c6.w,  c7.x, c7.y, c7.z, c7.w };
    float a[ROWS][MLP_D];
#pragma unroll
    for (int r = 0; r < ROWS; ++r) {
#pragma unroll
        for (int j = 0; j < MLP_D; ++j) {
            float acc = fmaf(h[r][0], W[j * MLP_D + 0], W[25 + j]);
#pragma unroll
            for (int i = 1; i < MLP_D; ++i)
                acc = fmaf(h[r][i], W[j * MLP_D + i], acc);
            a[r][j] = acc;
        }
    }
#pragma unroll
    for (int r = 0; r < ROWS; ++r)
#pragma unroll
        for (int j = 0; j < MLP_D; ++j)
            h[r][j] = fmaxf(a[r][j], 0.0f);
}

__global__ __launch_bounds__(256, 4) void MLP_89687507075104_kernel(
    const float* __restrict__ x,    // [n, 5]
    const f4* __restrict__ wq,      // prep'd: 8 f4/layer, 65 layers + tail
    float* __restrict__ out,        // [n]
    int n)
{
    const int t = blockIdx.x * blockDim.x + threadIdx.x;
    const long row0 = (long)t * ROWS;
    if (row0 >= n) return;

    // rows row0..row0+3 = 20 contiguous floats (80 B, 16B-aligned).
    const f4* xp = reinterpret_cast<const f4*>(x + row0 * MLP_D);
    const f4 q0 = xp[0], q1 = xp[1], q2 = xp[2], q3 = xp[3], q4 = xp[4];
    float h[ROWS][MLP_D];
    h[0][0]=q0.x; h[0][1]=q0.y; h[0][2]=q0.z; h[0][3]=q0.w; h[0][4]=q1.x;
    h[1][0]=q1.y; h[1][1]=q1.z; h[1][2]=q1.w; h[1][3]=q2.x; h[1][4]=q2.y;
    h[2][0]=q2.z; h[2][1]=q2.w; h[2][2]=q3.x; h[2][3]=q3.y; h[2][4]=q3.z;
    h[3][0]=q3.w; h[3][1]=q4.x; h[3][2]=q4.y; h[3][3]=q4.z; h[3][4]=q4.w;

    f4 A0,A1,A2,A3,A4,A5,A6,A7, B0,B1,B2,B3,B4,B5,B6,B7;

    // Prologue: issue layer 0's loads into A (no wait yet).
    asm volatile(
        "global_load_dwordx4 %0, %8, off\n\t"
        "global_load_dwordx4 %1, %8, off offset:16\n\t"
        "global_load_dwordx4 %2, %8, off offset:32\n\t"
        "global_load_dwordx4 %3, %8, off offset:48\n\t"
        "global_load_dwordx4 %4, %8, off offset:64\n\t"
        "global_load_dwordx4 %5, %8, off offset:80\n\t"
        "global_load_dwordx4 %6, %8, off offset:96\n\t"
        "global_load_dwordx4 %7, %8, off offset:112"
        : "=v"(A0),"=v"(A1),"=v"(A2),"=v"(A3),
          "=v"(A4),"=v"(A5),"=v"(A6),"=v"(A7)
        : "v"(wq));

#pragma unroll
    for (int l = 0; l < MLP_DEPTH; l += 2) {
        // Wait A (layer l) ready; prefetch layer l+1 into B; compute from A.
        PREFETCH_WAIT(B0,B1,B2,B3,B4,B5,B6,B7,
                      A0,A1,A2,A3,A4,A5,A6,A7, wq + (l + 1) * 8);
        layer_step(h, A0,A1,A2,A3,A4,A5,A6,A7);
        // Wait B (layer l+1) ready; prefetch layer l+2 into A (l=62 ->
        // layer 64 = zero sink); compute from B.
        PREFETCH_WAIT(A0,A1,A2,A3,A4,A5,A6,A7,
                      B0,B1,B2,B3,B4,B5,B6,B7, wq + (l + 2) * 8);
        layer_step(h, B0,B1,B2,B3,B4,B5,B6,B7);
    }

    // Drain: zero-layer loads into A are still in flight; their dest regs
    // must not be reused by the epilogue until writeback lands.
    asm volatile("s_waitcnt vmcnt(0)"
        : "+v"(A0),"+v"(A1),"+v"(A2),"+v"(A3),
          "+v"(A4),"+v"(A5),"+v"(A6),"+v"(A7));

    // Output layer: Linear(5,1). Tail at wq[65*8 .. 65*8+1].
    const f4 c0 = wq[65 * 8 + 0];
    const f4 c1 = wq[65 * 8 + 1];
    float o[ROWS];
#pragma unroll
    for (int r = 0; r < ROWS; ++r) {
        float acc = fmaf(h[r][0], c0.x, c1.y);   // b_out as VOP3 addend
        acc = fmaf(h[r][1], c0.y, acc);
        acc = fmaf(h[r][2], c0.z, acc);
        acc = fmaf(h[r][3], c0.w, acc);
        acc = fmaf(h[r][4], c1.x, acc);
        o[r] = acc;
    }
    f4 ov;
    ov.x = o[0]; ov.y = o[1]; ov.z = o[2]; ov.w = o[3];
    *reinterpret_cast<f4*>(out + row0) = ov;
}

extern "C" void kernel_launch(void* const* d_in, const int* in_sizes, int n_in,
                              void* d_out, int out_size, void* d_ws, size_t ws_size,
                              hipStream_t stream) {
    const float* x     = (const float*)d_in[0];
    const float* Ws    = (const float*)d_in[1];
    const float* bs    = (const float*)d_in[2];
    const float* W_out = (const float*)d_in[3];
    const float* b_out = (const float*)d_in[4];
    float* out = (float*)d_out;
    float* ws  = (float*)d_ws;   // needs (65*32+8)*4 = 8352 B

    const int n = in_sizes[0] / MLP_D;  // batch rows (1048576)

    const int nprep = 65 * 32 + 8;
    MLP_prep_kernel<<<(nprep + 255) / 256, 256, 0, stream>>>(Ws, bs, W_out, b_out, ws);

    const int block = 256;
    const int threads_needed = (n + ROWS - 1) / ROWS;
    const int grid = (threads_needed + block - 1) / block;  // 1024
    MLP_89687507075104_kernel<<<grid, block, 0, stream>>>(
        x, reinterpret_cast<const f4*>(ws), out, n);
}

// Round 12
// 123.787 us; speedup vs baseline: 1.0535x; 1.0535x over previous
//
#include <hip/hip_runtime.h>

// MLP: 64 × (Linear(5,5)+ReLU) then Linear(5,1), BATCH = 1048576 rows.
// fp32 VALU compute-bound; scalar v_fma_f32 is the fp32 peak on CDNA4.
//
// R12: isolate the R10/R11 bloat source. R4 (70 VALU + 30 dwordx2, 49 µs)
// beat R10/R11 (60 VALU + 8 dwordx4, 60-69 µs) despite fewer ideal ops —
// the only structural difference: R10/R11 repacked float4 loads through a
// `float W[32]` array before the FMAs (+32 v_mov/layer if SROA fails).
// R12 = R10's shape with FMAs consuming float4 components DIRECTLY by
// name. Per layer per thread (2 rows): 50 fma (bias = first fma's VOP3
// addend, from c6/c7 components) + 10 max = 60 VALU + 8 dwordx4.
// 2 rows/thread -> 2048 blocks = 8 waves/SIMD (max occupancy).
//
// Weight layout per layer (prep kernel, [64][32] floats):
//   c0=(W00 W01 W02 W03) c1=(W04 W10 W11 W12) c2=(W13 W14 W20 W21)
//   c3=(W22 W23 W24 W30) c4=(W31 W32 W33 W34) c5=(W40 W41 W42 W43)
//   c6=(W44 b0 b1 b2)    c7=(b3 b4 pad pad)
// Tail at [2048]: W_out[0..4], b_out, pad, pad.

#define MLP_DEPTH 64
#define MLP_D 5
#define ROWS 2

__global__ __launch_bounds__(256) void MLP_prep_kernel(
    const float* __restrict__ Ws, const float* __restrict__ bs,
    const float* __restrict__ W_out, const float* __restrict__ b_out,
    float* __restrict__ ws)
{
    const int idx = blockIdx.x * blockDim.x + threadIdx.x;
    if (idx < MLP_DEPTH * 32) {
        const int l = idx >> 5, k = idx & 31;
        float v = 0.0f;
        if (k < 25) v = Ws[l * 25 + k];
        else if (k < 30) v = bs[l * MLP_D + (k - 25)];
        ws[idx] = v;
    } else if (idx < MLP_DEPTH * 32 + 8) {
        const int k = idx - MLP_DEPTH * 32;
        float v = 0.0f;
        if (k < MLP_D) v = W_out[k];
        else if (k == MLP_D) v = b_out[0];
        ws[idx] = v;
    }
}

typedef float f2v __attribute__((ext_vector_type(2)));

__global__ __launch_bounds__(256) void MLP_89687507075104_kernel(
    const float* __restrict__ x,      // [n, 5]
    const float4* __restrict__ wq,    // prep'd: 8 float4/layer + 2 tail
    float* __restrict__ out,          // [n]
    int n)
{
    const int t = blockIdx.x * blockDim.x + threadIdx.x;
    const long row0 = (long)t * ROWS;
    if (row0 >= n) return;

    // rows row0,row0+1 = 10 contiguous floats (40 B, 8B-aligned f2 loads).
    const f2v* xp = reinterpret_cast<const f2v*>(x + row0 * MLP_D);
    const f2v v0 = xp[0], v1 = xp[1], v2 = xp[2], v3 = xp[3], v4 = xp[4];
    float h0[MLP_D], h1[MLP_D];
    h0[0] = v0.x; h0[1] = v0.y; h0[2] = v1.x; h0[3] = v1.y; h0[4] = v2.x;
    h1[0] = v2.y; h1[1] = v3.x; h1[2] = v3.y; h1[3] = v4.x; h1[4] = v4.y;

#pragma unroll
    for (int l = 0; l < MLP_DEPTH; ++l) {
        const float4* wp = wq + l * 8;
        const float4 c0 = wp[0], c1 = wp[1], c2 = wp[2], c3 = wp[3];
        const float4 c4 = wp[4], c5 = wp[5], c6 = wp[6], c7 = wp[7];

        // FMAs consume components directly — no intermediate array.
#define LAYER_ROW(h, a0, a1, a2, a3, a4)                      \
        float a0 = fmaf(h[0], c0.x, c6.y);                    \
        a0 = fmaf(h[1], c0.y, a0);                            \
        a0 = fmaf(h[2], c0.z, a0);                            \
        a0 = fmaf(h[3], c0.w, a0);                            \
        a0 = fmaf(h[4], c1.x, a0);                            \
        float a1 = fmaf(h[0], c1.y, c6.z);                    \
        a1 = fmaf(h[1], c1.z, a1);                            \
        a1 = fmaf(h[2], c1.w, a1);                            \
        a1 = fmaf(h[3], c2.x, a1);                            \
        a1 = fmaf(h[4], c2.y, a1);                            \
        float a2 = fmaf(h[0], c2.z, c6.w);                    \
        a2 = fmaf(h[1], c2.w, a2);                            \
        a2 = fmaf(h[2], c3.x, a2);                            \
        a2 = fmaf(h[3], c3.y, a2);                            \
        a2 = fmaf(h[4], c3.z, a2);                            \
        float a3 = fmaf(h[0], c3.w, c7.x);                    \
        a3 = fmaf(h[1], c4.x, a3);                            \
        a3 = fmaf(h[2], c4.y, a3);                            \
        a3 = fmaf(h[3], c4.z, a3);                            \
        a3 = fmaf(h[4], c4.w, a3);                            \
        float a4 = fmaf(h[0], c5.x, c7.y);                    \
        a4 = fmaf(h[1], c5.y, a4);                            \
        a4 = fmaf(h[2], c5.z, a4);                            \
        a4 = fmaf(h[3], c5.w, a4);                            \
        a4 = fmaf(h[4], c6.x, a4);                            \
        h[0] = fmaxf(a0, 0.0f);                               \
        h[1] = fmaxf(a1, 0.0f);                               \
        h[2] = fmaxf(a2, 0.0f);                               \
        h[3] = fmaxf(a3, 0.0f);                               \
        h[4] = fmaxf(a4, 0.0f);

        { LAYER_ROW(h0, p0, p1, p2, p3, p4) }
        { LAYER_ROW(h1, q0, q1, q2, q3, q4) }
#undef LAYER_ROW
    }

    // Output layer: Linear(5,1). Tail at wq[512..513].
    const float4 c0 = wq[MLP_DEPTH * 8 + 0];
    const float4 c1 = wq[MLP_DEPTH * 8 + 1];
    f2v o;
    {
        float acc = fmaf(h0[0], c0.x, c1.y);   // b_out as VOP3 addend
        acc = fmaf(h0[1], c0.y, acc);
        acc = fmaf(h0[2], c0.z, acc);
        acc = fmaf(h0[3], c0.w, acc);
        acc = fmaf(h0[4], c1.x, acc);
        o.x = acc;
    }
    {
        float acc = fmaf(h1[0], c0.x, c1.y);
        acc = fmaf(h1[1], c0.y, acc);
        acc = fmaf(h1[2], c0.z, acc);
        acc = fmaf(h1[3], c0.w, acc);
        acc = fmaf(h1[4], c1.x, acc);
        o.y = acc;
    }
    *reinterpret_cast<f2v*>(out + row0) = o;
}

extern "C" void kernel_launch(void* const* d_in, const int* in_sizes, int n_in,
                              void* d_out, int out_size, void* d_ws, size_t ws_size,
                              hipStream_t stream) {
    const float* x     = (const float*)d_in[0];
    const float* Ws    = (const float*)d_in[1];
    const float* bs    = (const float*)d_in[2];
    const float* W_out = (const float*)d_in[3];
    const float* b_out = (const float*)d_in[4];
    float* out = (float*)d_out;
    float* ws  = (float*)d_ws;   // needs 2056*4 = 8224 B

    const int n = in_sizes[0] / MLP_D;  // batch rows (1048576)

    const int nprep = MLP_DEPTH * 32 + 8;
    MLP_prep_kernel<<<(nprep + 255) / 256, 256, 0, stream>>>(Ws, bs, W_out, b_out, ws);

    const int block = 256;
    const int threads_needed = (n + ROWS - 1) / ROWS;
    const int grid = (threads_needed + block - 1) / block;  // 2048
    MLP_89687507075104_kernel<<<grid, block, 0, stream>>>(
        x, reinterpret_cast<const float4*>(ws), out, n);
}